// Round 1
// 607.592 us; speedup vs baseline: 1.1202x; 1.1202x over previous
//
#include <hip/hip_runtime.h>
#include <hip/hip_bf16.h>
#include <cstddef>

#define B_ 4
#define S_ 1024
#define E_ 1024
#define H_ 16
#define D_ 64
#define BH_ (B_*H_)

typedef __attribute__((ext_vector_type(8))) short short8;    // 8 bf16
typedef __attribute__((ext_vector_type(4))) float f32x4;
typedef __attribute__((ext_vector_type(4))) unsigned short us4;
typedef unsigned short u16;

__device__ inline u16 f2b(float x) {
    return __builtin_bit_cast(u16, __float2bfloat16(x));
}
__device__ inline float b2f(u16 u) {
    return __bfloat162float(__builtin_bit_cast(__hip_bfloat16, u));
}
__device__ inline void splitf(float x, u16& h, u16& l) {
    h = f2b(x); l = f2b(x - b2f(h));
}

__device__ inline void split_one(const float* __restrict__ in,
                                 u16* __restrict__ oh, u16* __restrict__ ol, int i)
{
    float4 v = ((const float4*)in)[i];
    us4 h, l;
    splitf(v.x, ((u16*)&h)[0], ((u16*)&l)[0]);
    splitf(v.y, ((u16*)&h)[1], ((u16*)&l)[1]);
    splitf(v.z, ((u16*)&h)[2], ((u16*)&l)[2]);
    splitf(v.w, ((u16*)&h)[3], ((u16*)&l)[3]);
    ((us4*)oh)[i] = h;
    ((us4*)ol)[i] = l;
}

// ---------------------------------------------------------------------------
// Fused prep: split x / W0 / W1 into hi/lo bf16 + xsum partial sums.
//   blocks [0,4096)        : split x       (1048576 float4)
//   blocks [4096,5120)     : split W0      (262144 float4)
//   blocks [5120,6144)     : split W1      (262144 float4)
//   blocks [6144,6400)     : xsum partials (16 s-chunks x 4 b x 4 k-blocks)
// xsum_p layout: [chunk16][b4][k1024] fp32 (aliased onto p1h region).
// ---------------------------------------------------------------------------
__global__ __launch_bounds__(256) void prep(
    const float* __restrict__ x, const float* __restrict__ W0,
    const float* __restrict__ W1, float* __restrict__ xsum_p,
    u16* __restrict__ xh, u16* __restrict__ xl,
    u16* __restrict__ w0h, u16* __restrict__ w0l,
    u16* __restrict__ w1h, u16* __restrict__ w1l)
{
    int bid = blockIdx.x, tid = threadIdx.x;
    if (bid < 4096) {
        split_one(x, xh, xl, bid * 256 + tid);
    } else if (bid < 5120) {
        split_one(W0, w0h, w0l, (bid - 4096) * 256 + tid);
    } else if (bid < 6144) {
        split_one(W1, w1h, w1l, (bid - 5120) * 256 + tid);
    } else {
        int p = bid - 6144;                 // [0,256)
        int kb = p & 3, b = (p >> 2) & 3, ch = p >> 4;
        int k = kb * 256 + tid;
        const float* base = x + ((size_t)(b * S_ + ch * 64)) * E_ + k;
        float s = 0.f;
#pragma unroll 8
        for (int j = 0; j < 64; ++j) s += base[(size_t)j * E_];
        xsum_p[(ch * 4 + b) * E_ + k] = s;
    }
}

// ---------------------------------------------------------------------------
// Fused t2 + M: grid (16 h, 4 b), 256 threads.
//   A) xs[k] = sum of 16 xsum partials  (LDS)
//   B) t2s[nn] = dot(W2[h*64+nn], xs) + S*b2   (LDS, wave-parallel)
//   C) MT[bh][c*64+a] = (1/8) * sum_d A[a][c][d] * t2s[d]  (hi/lo bf16)
// ---------------------------------------------------------------------------
__global__ __launch_bounds__(256) void t2k_M(
    const float* __restrict__ W2, const float* __restrict__ b2v,
    const float* __restrict__ xsum_p, const float* __restrict__ A,
    u16* __restrict__ MTh, u16* __restrict__ MTl)
{
    int h = blockIdx.x, b = blockIdx.y, tid = threadIdx.x;
    __shared__ float xs[1024];
    __shared__ float t2s[64];

#pragma unroll
    for (int j = 0; j < 4; ++j) {
        int k = j * 256 + tid;
        float s = 0.f;
#pragma unroll
        for (int c = 0; c < 16; ++c) s += xsum_p[(c * 4 + b) * E_ + k];
        xs[k] = s;
    }
    __syncthreads();

    int w = tid >> 6, lane = tid & 63;
    for (int nn = w; nn < 64; nn += 4) {
        int n = h * 64 + nn;
        const float* wr = W2 + (size_t)n * E_;
        float s = 0.f;
#pragma unroll
        for (int t = 0; t < 16; ++t) s = fmaf(wr[t * 64 + lane], xs[t * 64 + lane], s);
#pragma unroll
        for (int off = 1; off < 64; off <<= 1) s += __shfl_xor(s, off, 64);
        if (lane == 0) t2s[nn] = s + 1024.0f * b2v[n];
    }
    __syncthreads();

    int bh = b * H_ + h;
    int c = tid & 63;
    int a0 = (tid >> 6) * 16;
    for (int a = a0; a < a0 + 16; ++a) {
        float s = 0.f;
        const float* Ap = A + ((size_t)a * 64 + c) * 64;
#pragma unroll 8
        for (int d = 0; d < 64; ++d) s = fmaf(Ap[d], t2s[d], s);
        u16 hh, ll; splitf(s * 0.125f, hh, ll);
        MTh[(size_t)bh * 4096 + c * 64 + a] = hh;
        MTl[(size_t)bh * 4096 + c * 64 + a] = ll;
    }
}

// ---------------------------------------------------------------------------
// FUSED split-bf16 GEMM, 128x64 tile, computing BOTH p0 (->q via C@M) and p1
// from one X staging pass. 3-MFMA split products per output. acc0 = X*W0^T,
// acc1 = X*W1^T. Epilogue: p1 hi/lo write (acc1), then q = (acc0+b0) @ M_bh
// via split MFMA through LDS (stride-72), hi/lo bf16 out.
// ---------------------------------------------------------------------------
__global__ __launch_bounds__(256) void gemm_qp1(
    const u16* __restrict__ Xh, const u16* __restrict__ Xl,
    const u16* __restrict__ W0h_, const u16* __restrict__ W0l_,
    const u16* __restrict__ W1h_, const u16* __restrict__ W1l_,
    const float* __restrict__ bias0, const float* __restrict__ bias1,
    const u16* __restrict__ MTh, const u16* __restrict__ MTl,
    u16* __restrict__ qh, u16* __restrict__ ql,
    u16* __restrict__ p1h, u16* __restrict__ p1l)
{
    const int K = 1024;
    __shared__ __align__(16) char smem[40960];
    u16* Xs_h  = (u16*)smem;             // 128*40
    u16* Xs_l  = Xs_h + 128 * 40;
    u16* W0s_h = Xs_l + 128 * 40;        // 64*40 each
    u16* W0s_l = W0s_h + 64 * 40;
    u16* W1s_h = W0s_l + 64 * 40;
    u16* W1s_l = W1s_h + 64 * 40;        // staging total 40960 B
    u16* Cs_h  = (u16*)smem;             // epilogue: 128*72
    u16* Cs_l  = Cs_h + 128 * 72;        // 36864 B (alias)

    const int tid = threadIdx.x;
    const int w = tid >> 6, lane = tid & 63;
    const int waveM = w & 1, waveN = w >> 1;
    const int quad = lane >> 4, l16 = lane & 15;
    const int bm = blockIdx.x, bn = blockIdx.y;

    const int xrow = tid >> 1, xko = (tid & 1) * 16;
    const int wrow = tid >> 2, wko = (tid & 3) * 8;

    const u16* xh_g  = Xh  + (size_t)(bm * 128 + xrow) * K + xko;
    const u16* xl_g  = Xl  + (size_t)(bm * 128 + xrow) * K + xko;
    const u16* w0h_g = W0h_ + (size_t)(bn * 64 + wrow) * K + wko;
    const u16* w0l_g = W0l_ + (size_t)(bn * 64 + wrow) * K + wko;
    const u16* w1h_g = W1h_ + (size_t)(bn * 64 + wrow) * K + wko;
    const u16* w1l_g = W1l_ + (size_t)(bn * 64 + wrow) * K + wko;

    f32x4 acc0[4][2] = {};
    f32x4 acc1[4][2] = {};

    for (int k0 = 0; k0 < K; k0 += 32) {
        uint4 xa = *(const uint4*)(xh_g + k0);
        uint4 xb = *(const uint4*)(xh_g + k0 + 8);
        uint4 xc = *(const uint4*)(xl_g + k0);
        uint4 xd = *(const uint4*)(xl_g + k0 + 8);
        uint4 w0a = *(const uint4*)(w0h_g + k0);
        uint4 w0c = *(const uint4*)(w0l_g + k0);
        uint4 w1a = *(const uint4*)(w1h_g + k0);
        uint4 w1c = *(const uint4*)(w1l_g + k0);
        __syncthreads();
        *(uint4*)&Xs_h[xrow * 40 + xko]     = xa;
        *(uint4*)&Xs_h[xrow * 40 + xko + 8] = xb;
        *(uint4*)&Xs_l[xrow * 40 + xko]     = xc;
        *(uint4*)&Xs_l[xrow * 40 + xko + 8] = xd;
        *(uint4*)&W0s_h[wrow * 40 + wko] = w0a;
        *(uint4*)&W0s_l[wrow * 40 + wko] = w0c;
        *(uint4*)&W1s_h[wrow * 40 + wko] = w1a;
        *(uint4*)&W1s_l[wrow * 40 + wko] = w1c;
        __syncthreads();

        short8 ah[4], al[4], b0h[2], b0l[2], b1h[2], b1l[2];
#pragma unroll
        for (int mt = 0; mt < 4; ++mt) {
            int r = (waveM * 64 + mt * 16 + l16) * 40 + quad * 8;
            ah[mt] = *(short8*)&Xs_h[r];
            al[mt] = *(short8*)&Xs_l[r];
        }
#pragma unroll
        for (int nt = 0; nt < 2; ++nt) {
            int r = (waveN * 32 + nt * 16 + l16) * 40 + quad * 8;
            b0h[nt] = *(short8*)&W0s_h[r];
            b0l[nt] = *(short8*)&W0s_l[r];
            b1h[nt] = *(short8*)&W1s_h[r];
            b1l[nt] = *(short8*)&W1s_l[r];
        }
#pragma unroll
        for (int mt = 0; mt < 4; ++mt)
#pragma unroll
            for (int nt = 0; nt < 2; ++nt) {
                acc0[mt][nt] = __builtin_amdgcn_mfma_f32_16x16x32_bf16(ah[mt], b0h[nt], acc0[mt][nt], 0, 0, 0);
                acc1[mt][nt] = __builtin_amdgcn_mfma_f32_16x16x32_bf16(ah[mt], b1h[nt], acc1[mt][nt], 0, 0, 0);
                acc0[mt][nt] = __builtin_amdgcn_mfma_f32_16x16x32_bf16(ah[mt], b0l[nt], acc0[mt][nt], 0, 0, 0);
                acc1[mt][nt] = __builtin_amdgcn_mfma_f32_16x16x32_bf16(ah[mt], b1l[nt], acc1[mt][nt], 0, 0, 0);
                acc0[mt][nt] = __builtin_amdgcn_mfma_f32_16x16x32_bf16(al[mt], b0h[nt], acc0[mt][nt], 0, 0, 0);
                acc1[mt][nt] = __builtin_amdgcn_mfma_f32_16x16x32_bf16(al[mt], b1h[nt], acc1[mt][nt], 0, 0, 0);
            }
    }

    const int bh = (bm >> 3) * H_ + bn;   // 8 m-blocks per batch; head = bn

    // ---- p1 epilogue (no LDS) ----
#pragma unroll
    for (int mt = 0; mt < 4; ++mt)
#pragma unroll
        for (int nt = 0; nt < 2; ++nt)
#pragma unroll
            for (int r = 0; r < 4; ++r) {
                int m = bm * 128 + waveM * 64 + mt * 16 + quad * 4 + r;
                int n = bn * 64 + waveN * 32 + nt * 16 + l16;
                float val = acc1[mt][nt][r] + bias1[n];
                int s = m & 1023, c = n & 63;
                size_t addr = ((size_t)bh * S_ + s) * 64 + c;
                u16 hh, ll; splitf(val, hh, ll);
                p1h[addr] = hh; p1l[addr] = ll;
            }

    // ---- q epilogue: q = (acc0 + b0) @ M_bh via split MFMA ----
    __syncthreads();
#pragma unroll
    for (int mt = 0; mt < 4; ++mt)
#pragma unroll
        for (int nt = 0; nt < 2; ++nt)
#pragma unroll
            for (int r = 0; r < 4; ++r) {
                int i = waveM * 64 + mt * 16 + quad * 4 + r;
                int a = waveN * 32 + nt * 16 + l16;
                float val = acc0[mt][nt][r] + bias0[bn * 64 + a];
                u16 hh, ll; splitf(val, hh, ll);
                Cs_h[i * 72 + a] = hh;
                Cs_l[i * 72 + a] = ll;
            }
    __syncthreads();

    const u16* MTh_b = MTh + (size_t)bh * 4096;
    const u16* MTl_b = MTl + (size_t)bh * 4096;
    f32x4 qacc[4][2] = {};
#pragma unroll
    for (int ch = 0; ch < 2; ++ch) {
        short8 mh[2], ml[2];
#pragma unroll
        for (int nt = 0; nt < 2; ++nt) {
            int c = waveN * 32 + nt * 16 + l16;
            mh[nt] = *(const short8*)&MTh_b[c * 64 + ch * 32 + quad * 8];
            ml[nt] = *(const short8*)&MTl_b[c * 64 + ch * 32 + quad * 8];
        }
#pragma unroll
        for (int mt = 0; mt < 4; ++mt) {
            int rr = (waveM * 64 + mt * 16 + l16) * 72 + ch * 32 + quad * 8;
            short8 ca = *(short8*)&Cs_h[rr];
            short8 cl = *(short8*)&Cs_l[rr];
#pragma unroll
            for (int nt = 0; nt < 2; ++nt) {
                qacc[mt][nt] = __builtin_amdgcn_mfma_f32_16x16x32_bf16(ca, mh[nt], qacc[mt][nt], 0, 0, 0);
                qacc[mt][nt] = __builtin_amdgcn_mfma_f32_16x16x32_bf16(ca, ml[nt], qacc[mt][nt], 0, 0, 0);
                qacc[mt][nt] = __builtin_amdgcn_mfma_f32_16x16x32_bf16(cl, mh[nt], qacc[mt][nt], 0, 0, 0);
            }
        }
    }
#pragma unroll
    for (int mt = 0; mt < 4; ++mt)
#pragma unroll
        for (int nt = 0; nt < 2; ++nt)
#pragma unroll
            for (int r = 0; r < 4; ++r) {
                int s = (bm & 7) * 128 + waveM * 64 + mt * 16 + quad * 4 + r;
                int c = waveN * 32 + nt * 16 + l16;
                size_t addr = ((size_t)bh * S_ + s) * 64 + c;
                u16 hh, ll; splitf(qacc[mt][nt][r], hh, ll);
                qh[addr] = hh; ql[addr] = ll;
            }
}

// ---------------------------------------------------------------------------
// plain bf16 GEMM 64x64 (verbatim — PASSING)
// mode 0: out bf16 TRANSPOSED heads layout vT[(bh*64 + d)*S + s]   (v)
// mode 1: out fp32 natural                                          (final)
// ---------------------------------------------------------------------------
__global__ __launch_bounds__(256) void gemm_plain(
    const u16* __restrict__ Xb, const float* __restrict__ Wf,
    const float* __restrict__ bias, u16* __restrict__ outB,
    float* __restrict__ outF, int mode)
{
    const int K = 1024;
    __shared__ __align__(16) u16 Xs[64 * 40];
    __shared__ __align__(16) u16 Ws[64 * 40];

    const int tid = threadIdx.x;
    const int w = tid >> 6, lane = tid & 63;
    const int waveM = w & 1, waveN = w >> 1;
    const int quad = lane >> 4, l16 = lane & 15;
    const int bm = blockIdx.x, bn = blockIdx.y;
    const int lrow = tid >> 2, lkoff = (tid & 3) * 8;

    const u16* xg = Xb + (size_t)(bm * 64 + lrow) * K + lkoff;
    const float* wg = Wf + (size_t)(bn * 64 + lrow) * K + lkoff;

    f32x4 acc[2][2] = {};

    for (int k0 = 0; k0 < K; k0 += 32) {
        uint4 xv = *(const uint4*)(xg + k0);
        float4 w0 = *(const float4*)(wg + k0);
        float4 w1 = *(const float4*)(wg + k0 + 4);
        short8 wp;
        ((u16*)&wp)[0] = f2b(w0.x); ((u16*)&wp)[1] = f2b(w0.y);
        ((u16*)&wp)[2] = f2b(w0.z); ((u16*)&wp)[3] = f2b(w0.w);
        ((u16*)&wp)[4] = f2b(w1.x); ((u16*)&wp)[5] = f2b(w1.y);
        ((u16*)&wp)[6] = f2b(w1.z); ((u16*)&wp)[7] = f2b(w1.w);
        __syncthreads();
        *(uint4*)&Xs[lrow * 40 + lkoff] = xv;
        *(short8*)&Ws[lrow * 40 + lkoff] = wp;
        __syncthreads();

        short8 af[2], bf_[2];
#pragma unroll
        for (int mt = 0; mt < 2; ++mt)
            af[mt] = *(short8*)&Xs[(waveM * 32 + mt * 16 + l16) * 40 + quad * 8];
#pragma unroll
        for (int nt = 0; nt < 2; ++nt)
            bf_[nt] = *(short8*)&Ws[(waveN * 32 + nt * 16 + l16) * 40 + quad * 8];
#pragma unroll
        for (int mt = 0; mt < 2; ++mt)
#pragma unroll
            for (int nt = 0; nt < 2; ++nt)
                acc[mt][nt] = __builtin_amdgcn_mfma_f32_16x16x32_bf16(af[mt], bf_[nt], acc[mt][nt], 0, 0, 0);
    }

#pragma unroll
    for (int mt = 0; mt < 2; ++mt)
#pragma unroll
        for (int nt = 0; nt < 2; ++nt)
#pragma unroll
            for (int r = 0; r < 4; ++r) {
                int m = bm * 64 + waveM * 32 + mt * 16 + quad * 4 + r;
                int n = bn * 64 + waveN * 32 + nt * 16 + l16;
                float val = acc[mt][nt][r] + bias[n];
                if (mode == 0) {
                    int b = m >> 10, s = m & 1023, h = n >> 6, c = n & 63;
                    outB[((size_t)((b * H_ + h) * 64 + c)) * S_ + s] = f2b(val);
                } else {
                    outF[(size_t)m * 1024 + n] = val;
                }
            }
}

// ---------------------------------------------------------------------------
// FUSED logits+softmax+PV + XCD swizzle. PV now double-buffered (Ps/vs alias
// the dead p1 staging buffers) -> ONE barrier per PV iteration instead of two.
// Safety: __syncthreads drains lgkmcnt, so a wave passing barrier(t+1) has
// completed its buf[cur] ds_reads of iteration t before any wave re-writes
// buf[cur] at iteration t+2.
// ---------------------------------------------------------------------------
__global__ __launch_bounds__(512) void logits_softmax_pv(
    const u16* __restrict__ qh, const u16* __restrict__ ql,
    const u16* __restrict__ p1h, const u16* __restrict__ p1l,
    const u16* __restrict__ vT, float* __restrict__ attn,
    u16* __restrict__ values)
{
    int bh = blockIdx.x, i0 = blockIdx.y * 32;
    int b = bh >> 4, h = bh & 15;
    int tid = threadIdx.x, w = tid >> 6, lane = tid & 63;
    int quad = lane >> 4, l16 = lane & 15;
    int wg = w >> 2, wj = w & 3;

    __shared__ __align__(16) char sm[60928];
    u16* qhs  = (u16*)sm;                 // 32*72 u16 = 4608 B
    u16* qls  = (u16*)(sm + 4608);
    u16* p1hs = (u16*)(sm + 9216);        // [2][64*72] = 18432 B
    u16* p1ls = (u16*)(sm + 27648);       // [2][64*72] = 18432 B -> 46080
    float* redm = (float*)(sm + 46080);   // [4][32] = 512 B
    float* reds = (float*)(sm + 46592);   // 512 B -> 47104
    // PV-phase aliases (p1 staging dead after QK):
    u16* Ps  = (u16*)(sm + 9216);         // [2][32*72] = 9216 B
    u16* vs_ = (u16*)(sm + 18432);        // [2][64*72] = 18432 B -> 36864

    {   // stage q (32x64 hi/lo)
        int row = tid >> 4, c0 = (tid & 15) * 4;
        size_t g = ((size_t)bh * S_ + i0 + row) * 64 + c0;
        *(us4*)&qhs[row * 72 + c0] = *(const us4*)&qh[g];
        *(us4*)&qls[row * 72 + c0] = *(const us4*)&ql[g];
    }

    // p1 staging: thread covers (row jl, 8 cols) — tile stride 4096 elems
    const int jl = tid >> 3, c0s = (tid & 7) * 8;
    const size_t gp = ((size_t)bh * S_ + jl) * 64 + c0s;

    uint4 rha = *(const uint4*)&p1h[gp];
    uint4 rla = *(const uint4*)&p1l[gp];
    *(uint4*)&p1hs[jl * 72 + c0s] = rha;
    *(uint4*)&p1ls[jl * 72 + c0s] = rla;
    uint4 rh1 = *(const uint4*)&p1h[gp + 4096];
    uint4 rl1 = *(const uint4*)&p1l[gp + 4096];
    __syncthreads();    // q + buf0 visible

    short8 ah[2], al[2];
#pragma unroll
    for (int ch = 0; ch < 2; ++ch) {
        ah[ch] = *(short8*)&qhs[(wg * 16 + l16) * 72 + ch * 32 + quad * 8];
        al[ch] = *(short8*)&qls[(wg * 16 + l16) * 72 + ch * 32 + quad * 8];
    }

    f32x4 L[16];
    for (int t = 0; t < 16; ++t) {
        int cur = t & 1;
        uint4 rh2, rl2;
        if (t < 14) {
            size_t gn = gp + (size_t)(t + 2) * 4096;
            rh2 = *(const uint4*)&p1h[gn];
            rl2 = *(const uint4*)&p1l[gn];
        }
        int jr = wj * 16 + l16;
        const u16* Hb = &p1hs[cur * 4608 + jr * 72];
        const u16* Lb = &p1ls[cur * 4608 + jr * 72];
        short8 bh0 = *(const short8*)(Hb + quad * 8);
        short8 bh1 = *(const short8*)(Hb + 32 + quad * 8);
        short8 bl0 = *(const short8*)(Lb + quad * 8);
        short8 bl1 = *(const short8*)(Lb + 32 + quad * 8);
        f32x4 a = {};
        a = __builtin_amdgcn_mfma_f32_16x16x32_bf16(ah[0], bh0, a, 0, 0, 0);
        a = __builtin_amdgcn_mfma_f32_16x16x32_bf16(ah[1], bh1, a, 0, 0, 0);
        a = __builtin_amdgcn_mfma_f32_16x16x32_bf16(ah[0], bl0, a, 0, 0, 0);
        a = __builtin_amdgcn_mfma_f32_16x16x32_bf16(ah[1], bl1, a, 0, 0, 0);
        a = __builtin_amdgcn_mfma_f32_16x16x32_bf16(al[0], bh0, a, 0, 0, 0);
        a = __builtin_amdgcn_mfma_f32_16x16x32_bf16(al[1], bh1, a, 0, 0, 0);
        L[t] = a;
        if (t < 15) {
            *(uint4*)&p1hs[(1 - cur) * 4608 + jl * 72 + c0s] = rh1;
            *(uint4*)&p1ls[(1 - cur) * 4608 + jl * 72 + c0s] = rl1;
            if (t < 14) { rh1 = rh2; rl1 = rl2; }
            __syncthreads();
        }
    }

    // softmax
    float mrow[4], srow[4];
#pragma unroll
    for (int r = 0; r < 4; ++r) {
        float m = L[0][r];
#pragma unroll
        for (int t = 1; t < 16; ++t) m = fmaxf(m, L[t][r]);
#pragma unroll
        for (int off = 1; off < 16; off <<= 1) m = fmaxf(m, __shfl_xor(m, off, 64));
        mrow[r] = m;
    }
    if (l16 == 0)
#pragma unroll
        for (int r = 0; r < 4; ++r) redm[wj * 32 + wg * 16 + quad * 4 + r] = mrow[r];
    __syncthreads();
#pragma unroll
    for (int r = 0; r < 4; ++r) {
        int rowg = wg * 16 + quad * 4 + r;
        float m = fmaxf(fmaxf(redm[0 * 32 + rowg], redm[1 * 32 + rowg]),
                        fmaxf(redm[2 * 32 + rowg], redm[3 * 32 + rowg]));
        float s = 0.f;
#pragma unroll
        for (int t = 0; t < 16; ++t) { L[t][r] = __expf(L[t][r] - m); s += L[t][r]; }
#pragma unroll
        for (int off = 1; off < 16; off <<= 1) s += __shfl_xor(s, off, 64);
        srow[r] = s;
    }
    if (l16 == 0)
#pragma unroll
        for (int r = 0; r < 4; ++r) reds[wj * 32 + wg * 16 + quad * 4 + r] = srow[r];
    __syncthreads();
#pragma unroll
    for (int r = 0; r < 4; ++r) {
        int rowg = wg * 16 + quad * 4 + r;
        float inv = 1.0f / (reds[0 * 32 + rowg] + reds[1 * 32 + rowg] +
                            reds[2 * 32 + rowg] + reds[3 * 32 + rowg]);
        float* arow = attn + ((size_t)bh * S_ + i0 + rowg) * S_;
#pragma unroll
        for (int t = 0; t < 16; ++t) {
            float p = L[t][r] * inv;
            L[t][r] = p;
            __builtin_nontemporal_store(p, &arow[t * 64 + wj * 16 + l16]);
        }
    }

    // ---- PV (double-buffered, 1 barrier/iter) ----
    const int dv = tid >> 3, jc = (tid & 7) * 8;
    size_t gv = ((size_t)(bh * 64 + dv)) * S_ + jc;
    uint4 rv = *(const uint4*)&vT[gv];

    f32x4 acc_pv = {};
    for (int t = 0; t < 16; ++t) {
        int cur = t & 1;
#pragma unroll
        for (int r = 0; r < 4; ++r)
            Ps[cur * 2304 + (wg * 16 + quad * 4 + r) * 72 + wj * 16 + l16] = f2b(L[t][r]);
        *(uint4*)&vs_[cur * 4608 + dv * 72 + jc] = rv;
        __syncthreads();
        if (t < 15) rv = *(const uint4*)&vT[gv + (size_t)(t + 1) * 64];
        int d = wj * 16 + l16;
#pragma unroll
        for (int cc = 0; cc < 64; cc += 32) {
            short8 af = *(short8*)&Ps[cur * 2304 + (wg * 16 + l16) * 72 + cc + quad * 8];
            short8 bf = *(short8*)&vs_[cur * 4608 + d * 72 + cc + quad * 8];
            acc_pv = __builtin_amdgcn_mfma_f32_16x16x32_bf16(af, bf, acc_pv, 0, 0, 0);
        }
    }
#pragma unroll
    for (int r = 0; r < 4; ++r) {
        int i = i0 + wg * 16 + quad * 4 + r;
        int d = wj * 16 + l16;
        values[((size_t)(b * S_ + i)) * E_ + h * 64 + d] = f2b(acc_pv[r]);
    }
}

extern "C" void kernel_launch(void* const* d_in, const int* in_sizes, int n_in,
                              void* d_out, int out_size, void* d_ws, size_t ws_size,
                              hipStream_t stream)
{
    const float* x  = (const float*)d_in[0];
    const float* W0 = (const float*)d_in[1];
    const float* b0 = (const float*)d_in[2];
    const float* W1 = (const float*)d_in[3];
    const float* b1 = (const float*)d_in[4];
    const float* W2 = (const float*)d_in[5];
    const float* b2 = (const float*)d_in[6];
    const float* Wv = (const float*)d_in[7];
    const float* bv = (const float*)d_in[8];
    const float* Wo = (const float*)d_in[9];
    const float* bo = (const float*)d_in[10];
    const float* A  = (const float*)d_in[11];

    float* out  = (float*)d_out;
    float* attn = out + (size_t)B_ * S_ * E_;

    // workspace (~76 MB)
    u16* xh  = (u16*)d_ws;                  // 8 MB
    u16* xl  = xh + 4194304;                // 8 MB
    u16* w0h = xl + 4194304;                // 2 MB
    u16* w0l = w0h + 1048576;
    u16* w1h = w0l + 1048576;
    u16* w1l = w1h + 1048576;
    u16* p1h = w1l + 1048576;               // 8 MB
    u16* p1l = p1h + 4194304;               // 8 MB
    u16* qh  = p1l + 4194304;               // 8 MB
    u16* ql  = qh + 4194304;                // 8 MB
    u16* vT  = ql + 4194304;                // 8 MB (heads-transposed v)
    u16* values = vT + 4194304;             // 8 MB (bf16 natural)
    u16* MTh = values + 4194304;            // 512 KB (transposed M hi)
    u16* MTl = MTh + 262144;                // 512 KB
    // xsum partials [16][4][1024] fp32 = 256 KB — aliased onto p1h (p1h is
    // written by gemm_qp1, which runs strictly after t2k_M consumed xsum_p).
    float* xsum_p = (float*)p1h;

    prep<<<6400, 256, 0, stream>>>(x, W0, W1, xsum_p, xh, xl, w0h, w0l, w1h, w1l);
    t2k_M<<<dim3(16, 4), 256, 0, stream>>>(W2, b2, xsum_p, A, MTh, MTl);

    gemm_qp1<<<dim3(32, 16), 256, 0, stream>>>(xh, xl, w0h, w0l, w1h, w1l,
                                               b0, b1, MTh, MTl, qh, ql, p1h, p1l);

    dim3 gp(64, 16);
    gemm_plain<<<gp, 256, 0, stream>>>(xh, Wv, bv, vT, nullptr, 0);               // vT

    logits_softmax_pv<<<dim3(64, 32), 512, 0, stream>>>(qh, ql, p1h, p1l, vT, attn, values);

    gemm_plain<<<gp, 256, 0, stream>>>(values, Wo, bo, nullptr, out, 1);
}

// Round 2
// 537.659 us; speedup vs baseline: 1.2659x; 1.1301x over previous
//
#include <hip/hip_runtime.h>
#include <hip/hip_bf16.h>
#include <cstddef>

#define B_ 4
#define S_ 1024
#define E_ 1024
#define H_ 16
#define D_ 64
#define BH_ (B_*H_)

typedef __attribute__((ext_vector_type(8))) short short8;    // 8 bf16
typedef __attribute__((ext_vector_type(4))) float f32x4;
typedef __attribute__((ext_vector_type(4))) unsigned short us4;
typedef unsigned short u16;

__device__ inline u16 f2b(float x) {
    return __builtin_bit_cast(u16, __float2bfloat16(x));
}
__device__ inline float b2f(u16 u) {
    return __bfloat162float(__builtin_bit_cast(__hip_bfloat16, u));
}
__device__ inline void splitf(float x, u16& h, u16& l) {
    h = f2b(x); l = f2b(x - b2f(h));
}

__device__ inline void split_one(const float* __restrict__ in,
                                 u16* __restrict__ oh, u16* __restrict__ ol, int i)
{
    float4 v = ((const float4*)in)[i];
    us4 h, l;
    splitf(v.x, ((u16*)&h)[0], ((u16*)&l)[0]);
    splitf(v.y, ((u16*)&h)[1], ((u16*)&l)[1]);
    splitf(v.z, ((u16*)&h)[2], ((u16*)&l)[2]);
    splitf(v.w, ((u16*)&h)[3], ((u16*)&l)[3]);
    ((us4*)oh)[i] = h;
    ((us4*)ol)[i] = l;
}

__device__ inline void conv_one(const float* __restrict__ in,
                                u16* __restrict__ ob, int i)
{
    float4 v = ((const float4*)in)[i];
    us4 h;
    ((u16*)&h)[0] = f2b(v.x); ((u16*)&h)[1] = f2b(v.y);
    ((u16*)&h)[2] = f2b(v.z); ((u16*)&h)[3] = f2b(v.w);
    ((us4*)ob)[i] = h;
}

// ---------------------------------------------------------------------------
// Fused prep: split x/W0/W1 hi/lo, convert Wv/Wo to bf16, xsum partials.
//   [0,4096)      split x        (1048576 float4)
//   [4096,5120)   split W0
//   [5120,6144)   split W1
//   [6144,7168)   convert Wv -> wvb (bf16 hi only)
//   [7168,8192)   convert Wo -> wob
//   [8192,8448)   xsum partials (16 s-chunks x 4 b x 4 k-blocks)
// ---------------------------------------------------------------------------
__global__ __launch_bounds__(256) void prep(
    const float* __restrict__ x, const float* __restrict__ W0,
    const float* __restrict__ W1, const float* __restrict__ Wv,
    const float* __restrict__ Wo, float* __restrict__ xsum_p,
    u16* __restrict__ xh, u16* __restrict__ xl,
    u16* __restrict__ w0h, u16* __restrict__ w0l,
    u16* __restrict__ w1h, u16* __restrict__ w1l,
    u16* __restrict__ wvb, u16* __restrict__ wob)
{
    int bid = blockIdx.x, tid = threadIdx.x;
    if (bid < 4096) {
        split_one(x, xh, xl, bid * 256 + tid);
    } else if (bid < 5120) {
        split_one(W0, w0h, w0l, (bid - 4096) * 256 + tid);
    } else if (bid < 6144) {
        split_one(W1, w1h, w1l, (bid - 5120) * 256 + tid);
    } else if (bid < 7168) {
        conv_one(Wv, wvb, (bid - 6144) * 256 + tid);
    } else if (bid < 8192) {
        conv_one(Wo, wob, (bid - 7168) * 256 + tid);
    } else {
        int p = bid - 8192;                 // [0,256)
        int kb = p & 3, b = (p >> 2) & 3, ch = p >> 4;
        int k = kb * 256 + tid;
        const float* base = x + ((size_t)(b * S_ + ch * 64)) * E_ + k;
        float s = 0.f;
#pragma unroll 8
        for (int j = 0; j < 64; ++j) s += base[(size_t)j * E_];
        xsum_p[(ch * 4 + b) * E_ + k] = s;
    }
}

// ---------------------------------------------------------------------------
// Fused t2 + M (unchanged, PASSING)
// ---------------------------------------------------------------------------
__global__ __launch_bounds__(256) void t2k_M(
    const float* __restrict__ W2, const float* __restrict__ b2v,
    const float* __restrict__ xsum_p, const float* __restrict__ A,
    u16* __restrict__ MTh, u16* __restrict__ MTl)
{
    int h = blockIdx.x, b = blockIdx.y, tid = threadIdx.x;
    __shared__ float xs[1024];
    __shared__ float t2s[64];

#pragma unroll
    for (int j = 0; j < 4; ++j) {
        int k = j * 256 + tid;
        float s = 0.f;
#pragma unroll
        for (int c = 0; c < 16; ++c) s += xsum_p[(c * 4 + b) * E_ + k];
        xs[k] = s;
    }
    __syncthreads();

    int w = tid >> 6, lane = tid & 63;
    for (int nn = w; nn < 64; nn += 4) {
        int n = h * 64 + nn;
        const float* wr = W2 + (size_t)n * E_;
        float s = 0.f;
#pragma unroll
        for (int t = 0; t < 16; ++t) s = fmaf(wr[t * 64 + lane], xs[t * 64 + lane], s);
#pragma unroll
        for (int off = 1; off < 64; off <<= 1) s += __shfl_xor(s, off, 64);
        if (lane == 0) t2s[nn] = s + 1024.0f * b2v[n];
    }
    __syncthreads();

    int bh = b * H_ + h;
    int c = tid & 63;
    int a0 = (tid >> 6) * 16;
    for (int a = a0; a < a0 + 16; ++a) {
        float s = 0.f;
        const float* Ap = A + ((size_t)a * 64 + c) * 64;
#pragma unroll 8
        for (int d = 0; d < 64; ++d) s = fmaf(Ap[d], t2s[d], s);
        u16 hh, ll; splitf(s * 0.125f, hh, ll);
        MTh[(size_t)bh * 4096 + c * 64 + a] = hh;
        MTl[(size_t)bh * 4096 + c * 64 + a] = ll;
    }
}

// ---------------------------------------------------------------------------
// qp1 body: split GEMM 128x64, both p0(->q via C@M) and p1 (verbatim R1 logic)
// ---------------------------------------------------------------------------
__device__ void qp1_body(
    const u16* __restrict__ Xh, const u16* __restrict__ Xl,
    const u16* __restrict__ W0h_, const u16* __restrict__ W0l_,
    const u16* __restrict__ W1h_, const u16* __restrict__ W1l_,
    const float* __restrict__ bias0, const float* __restrict__ bias1,
    const u16* __restrict__ MTh, const u16* __restrict__ MTl,
    u16* __restrict__ qh, u16* __restrict__ ql,
    u16* __restrict__ p1h, u16* __restrict__ p1l,
    int bm, int bn, char* smem)
{
    const int K = 1024;
    u16* Xs_h  = (u16*)smem;             // 128*40
    u16* Xs_l  = Xs_h + 128 * 40;
    u16* W0s_h = Xs_l + 128 * 40;        // 64*40 each
    u16* W0s_l = W0s_h + 64 * 40;
    u16* W1s_h = W0s_l + 64 * 40;
    u16* W1s_l = W1s_h + 64 * 40;        // staging total 40960 B
    u16* Cs_h  = (u16*)smem;             // epilogue: 128*72
    u16* Cs_l  = Cs_h + 128 * 72;        // 36864 B (alias)

    const int tid = threadIdx.x;
    const int w = tid >> 6, lane = tid & 63;
    const int waveM = w & 1, waveN = w >> 1;
    const int quad = lane >> 4, l16 = lane & 15;

    const int xrow = tid >> 1, xko = (tid & 1) * 16;
    const int wrow = tid >> 2, wko = (tid & 3) * 8;

    const u16* xh_g  = Xh  + (size_t)(bm * 128 + xrow) * K + xko;
    const u16* xl_g  = Xl  + (size_t)(bm * 128 + xrow) * K + xko;
    const u16* w0h_g = W0h_ + (size_t)(bn * 64 + wrow) * K + wko;
    const u16* w0l_g = W0l_ + (size_t)(bn * 64 + wrow) * K + wko;
    const u16* w1h_g = W1h_ + (size_t)(bn * 64 + wrow) * K + wko;
    const u16* w1l_g = W1l_ + (size_t)(bn * 64 + wrow) * K + wko;

    f32x4 acc0[4][2] = {};
    f32x4 acc1[4][2] = {};

    for (int k0 = 0; k0 < K; k0 += 32) {
        uint4 xa = *(const uint4*)(xh_g + k0);
        uint4 xb = *(const uint4*)(xh_g + k0 + 8);
        uint4 xc = *(const uint4*)(xl_g + k0);
        uint4 xd = *(const uint4*)(xl_g + k0 + 8);
        uint4 w0a = *(const uint4*)(w0h_g + k0);
        uint4 w0c = *(const uint4*)(w0l_g + k0);
        uint4 w1a = *(const uint4*)(w1h_g + k0);
        uint4 w1c = *(const uint4*)(w1l_g + k0);
        __syncthreads();
        *(uint4*)&Xs_h[xrow * 40 + xko]     = xa;
        *(uint4*)&Xs_h[xrow * 40 + xko + 8] = xb;
        *(uint4*)&Xs_l[xrow * 40 + xko]     = xc;
        *(uint4*)&Xs_l[xrow * 40 + xko + 8] = xd;
        *(uint4*)&W0s_h[wrow * 40 + wko] = w0a;
        *(uint4*)&W0s_l[wrow * 40 + wko] = w0c;
        *(uint4*)&W1s_h[wrow * 40 + wko] = w1a;
        *(uint4*)&W1s_l[wrow * 40 + wko] = w1c;
        __syncthreads();

        short8 ah[4], al[4], b0h[2], b0l[2], b1h[2], b1l[2];
#pragma unroll
        for (int mt = 0; mt < 4; ++mt) {
            int r = (waveM * 64 + mt * 16 + l16) * 40 + quad * 8;
            ah[mt] = *(short8*)&Xs_h[r];
            al[mt] = *(short8*)&Xs_l[r];
        }
#pragma unroll
        for (int nt = 0; nt < 2; ++nt) {
            int r = (waveN * 32 + nt * 16 + l16) * 40 + quad * 8;
            b0h[nt] = *(short8*)&W0s_h[r];
            b0l[nt] = *(short8*)&W0s_l[r];
            b1h[nt] = *(short8*)&W1s_h[r];
            b1l[nt] = *(short8*)&W1s_l[r];
        }
#pragma unroll
        for (int mt = 0; mt < 4; ++mt)
#pragma unroll
            for (int nt = 0; nt < 2; ++nt) {
                acc0[mt][nt] = __builtin_amdgcn_mfma_f32_16x16x32_bf16(ah[mt], b0h[nt], acc0[mt][nt], 0, 0, 0);
                acc1[mt][nt] = __builtin_amdgcn_mfma_f32_16x16x32_bf16(ah[mt], b1h[nt], acc1[mt][nt], 0, 0, 0);
                acc0[mt][nt] = __builtin_amdgcn_mfma_f32_16x16x32_bf16(ah[mt], b0l[nt], acc0[mt][nt], 0, 0, 0);
                acc1[mt][nt] = __builtin_amdgcn_mfma_f32_16x16x32_bf16(ah[mt], b1l[nt], acc1[mt][nt], 0, 0, 0);
                acc0[mt][nt] = __builtin_amdgcn_mfma_f32_16x16x32_bf16(al[mt], b0h[nt], acc0[mt][nt], 0, 0, 0);
                acc1[mt][nt] = __builtin_amdgcn_mfma_f32_16x16x32_bf16(al[mt], b1h[nt], acc1[mt][nt], 0, 0, 0);
            }
    }

    const int bh = (bm >> 3) * H_ + bn;   // 8 m-blocks per batch; head = bn

    // ---- p1 epilogue (no LDS) ----
#pragma unroll
    for (int mt = 0; mt < 4; ++mt)
#pragma unroll
        for (int nt = 0; nt < 2; ++nt)
#pragma unroll
            for (int r = 0; r < 4; ++r) {
                int m = bm * 128 + waveM * 64 + mt * 16 + quad * 4 + r;
                int n = bn * 64 + waveN * 32 + nt * 16 + l16;
                float val = acc1[mt][nt][r] + bias1[n];
                int s = m & 1023, c = n & 63;
                size_t addr = ((size_t)bh * S_ + s) * 64 + c;
                u16 hh, ll; splitf(val, hh, ll);
                p1h[addr] = hh; p1l[addr] = ll;
            }

    // ---- q epilogue: q = (acc0 + b0) @ M_bh via split MFMA ----
    __syncthreads();
#pragma unroll
    for (int mt = 0; mt < 4; ++mt)
#pragma unroll
        for (int nt = 0; nt < 2; ++nt)
#pragma unroll
            for (int r = 0; r < 4; ++r) {
                int i = waveM * 64 + mt * 16 + quad * 4 + r;
                int a = waveN * 32 + nt * 16 + l16;
                float val = acc0[mt][nt][r] + bias0[bn * 64 + a];
                u16 hh, ll; splitf(val, hh, ll);
                Cs_h[i * 72 + a] = hh;
                Cs_l[i * 72 + a] = ll;
            }
    __syncthreads();

    const u16* MTh_b = MTh + (size_t)bh * 4096;
    const u16* MTl_b = MTl + (size_t)bh * 4096;
    f32x4 qacc[4][2] = {};
#pragma unroll
    for (int ch = 0; ch < 2; ++ch) {
        short8 mh[2], ml[2];
#pragma unroll
        for (int nt = 0; nt < 2; ++nt) {
            int c = waveN * 32 + nt * 16 + l16;
            mh[nt] = *(const short8*)&MTh_b[c * 64 + ch * 32 + quad * 8];
            ml[nt] = *(const short8*)&MTl_b[c * 64 + ch * 32 + quad * 8];
        }
#pragma unroll
        for (int mt = 0; mt < 4; ++mt) {
            int rr = (waveM * 64 + mt * 16 + l16) * 72 + ch * 32 + quad * 8;
            short8 ca = *(short8*)&Cs_h[rr];
            short8 cl = *(short8*)&Cs_l[rr];
#pragma unroll
            for (int nt = 0; nt < 2; ++nt) {
                qacc[mt][nt] = __builtin_amdgcn_mfma_f32_16x16x32_bf16(ca, mh[nt], qacc[mt][nt], 0, 0, 0);
                qacc[mt][nt] = __builtin_amdgcn_mfma_f32_16x16x32_bf16(ca, ml[nt], qacc[mt][nt], 0, 0, 0);
                qacc[mt][nt] = __builtin_amdgcn_mfma_f32_16x16x32_bf16(cl, mh[nt], qacc[mt][nt], 0, 0, 0);
            }
        }
    }
#pragma unroll
    for (int mt = 0; mt < 4; ++mt)
#pragma unroll
        for (int nt = 0; nt < 2; ++nt)
#pragma unroll
            for (int r = 0; r < 4; ++r) {
                int s = (bm & 7) * 128 + waveM * 64 + mt * 16 + quad * 4 + r;
                int c = waveN * 32 + nt * 16 + l16;
                size_t addr = ((size_t)bh * S_ + s) * 64 + c;
                u16 hh, ll; splitf(qacc[mt][nt][r], hh, ll);
                qh[addr] = hh; ql[addr] = ll;
            }
}

// ---------------------------------------------------------------------------
// plain bf16 GEMM body, 128x64 tile, pre-converted bf16 W.
// mode 0: bf16 transposed heads layout vT[(bh*64+d)*S + s]
// mode 1: fp32 natural out
// ---------------------------------------------------------------------------
__device__ void plain128_body(
    const u16* __restrict__ Xb, const u16* __restrict__ Wb,
    const float* __restrict__ bias, u16* __restrict__ outB,
    float* __restrict__ outF, int mode, int bm, int bn, char* smem)
{
    const int K = 1024;
    u16* Xs = (u16*)smem;                // 128*40
    u16* Ws = Xs + 128 * 40;             // 64*40  (total 15360 B)

    const int tid = threadIdx.x;
    const int w = tid >> 6, lane = tid & 63;
    const int waveM = w & 1, waveN = w >> 1;
    const int quad = lane >> 4, l16 = lane & 15;
    const int xrow = tid >> 1, xko = (tid & 1) * 16;
    const int wrow = tid >> 2, wko = (tid & 3) * 8;

    const u16* xg = Xb + (size_t)(bm * 128 + xrow) * K + xko;
    const u16* wg = Wb + (size_t)(bn * 64 + wrow) * K + wko;

    f32x4 acc[4][2] = {};

    for (int k0 = 0; k0 < K; k0 += 32) {
        uint4 xa = *(const uint4*)(xg + k0);
        uint4 xb = *(const uint4*)(xg + k0 + 8);
        uint4 wa = *(const uint4*)(wg + k0);
        __syncthreads();
        *(uint4*)&Xs[xrow * 40 + xko]     = xa;
        *(uint4*)&Xs[xrow * 40 + xko + 8] = xb;
        *(uint4*)&Ws[wrow * 40 + wko]     = wa;
        __syncthreads();

        short8 af[4], bf_[2];
#pragma unroll
        for (int mt = 0; mt < 4; ++mt)
            af[mt] = *(short8*)&Xs[(waveM * 64 + mt * 16 + l16) * 40 + quad * 8];
#pragma unroll
        for (int nt = 0; nt < 2; ++nt)
            bf_[nt] = *(short8*)&Ws[(waveN * 32 + nt * 16 + l16) * 40 + quad * 8];
#pragma unroll
        for (int mt = 0; mt < 4; ++mt)
#pragma unroll
            for (int nt = 0; nt < 2; ++nt)
                acc[mt][nt] = __builtin_amdgcn_mfma_f32_16x16x32_bf16(af[mt], bf_[nt], acc[mt][nt], 0, 0, 0);
    }

#pragma unroll
    for (int mt = 0; mt < 4; ++mt)
#pragma unroll
        for (int nt = 0; nt < 2; ++nt)
#pragma unroll
            for (int r = 0; r < 4; ++r) {
                int m = bm * 128 + waveM * 64 + mt * 16 + quad * 4 + r;
                int n = bn * 64 + waveN * 32 + nt * 16 + l16;
                float val = acc[mt][nt][r] + bias[n];
                if (mode == 0) {
                    int b = m >> 10, s = m & 1023, h = n >> 6, c = n & 63;
                    outB[((size_t)((b * H_ + h) * 64 + c)) * S_ + s] = f2b(val);
                } else {
                    outF[(size_t)m * 1024 + n] = val;
                }
            }
}

// ---------------------------------------------------------------------------
// merged mid kernel: blocks [0,512) qp1, [512,1024) vT gemm — one launch,
// vT blocks backfill qp1's occupancy tail.
// ---------------------------------------------------------------------------
__global__ __launch_bounds__(256) void gemm_mid(
    const u16* __restrict__ xh, const u16* __restrict__ xl,
    const u16* __restrict__ w0h, const u16* __restrict__ w0l,
    const u16* __restrict__ w1h, const u16* __restrict__ w1l,
    const float* __restrict__ b0, const float* __restrict__ b1,
    const u16* __restrict__ MTh, const u16* __restrict__ MTl,
    u16* __restrict__ qh, u16* __restrict__ ql,
    u16* __restrict__ p1h, u16* __restrict__ p1l,
    const u16* __restrict__ wvb, const float* __restrict__ bv,
    u16* __restrict__ vT)
{
    __shared__ __align__(16) char smem[40960];
    int bid = blockIdx.x;
    if (bid < 512) {
        qp1_body(xh, xl, w0h, w0l, w1h, w1l, b0, b1, MTh, MTl,
                 qh, ql, p1h, p1l, bid & 31, bid >> 5, smem);
    } else {
        int b2 = bid - 512;
        plain128_body(xh, wvb, bv, vT, nullptr, 0, b2 & 31, b2 >> 5, smem);
    }
}

// final GEMM: out = values @ Wo^T + bo (fp32 out)
__global__ __launch_bounds__(256) void gemm_fin(
    const u16* __restrict__ values, const u16* __restrict__ wob,
    const float* __restrict__ bo, float* __restrict__ out)
{
    __shared__ __align__(16) char smem[15360];
    plain128_body(values, wob, bo, nullptr, out, 1, blockIdx.x, blockIdx.y, smem);
}

// ---------------------------------------------------------------------------
// FUSED logits+softmax+PV + XCD swizzle. QK double-buffered (1 barrier/iter).
// PV now processes 2 KV-tiles per barrier (8 barriers instead of 16);
// accumulation order bitwise identical to R1.
// LDS (56320 B): QK: qhs[0,4608) qls[4608,9216) p1hs[9216,27648)
// p1ls[27648,46080). PV alias: Ps[0,18432)=[2buf][2t][32*72],
// vs[18432,55296)=[2buf][2t][64*72]. redm/reds [55296,56320).
// ---------------------------------------------------------------------------
__global__ __launch_bounds__(512) void logits_softmax_pv(
    const u16* __restrict__ qh, const u16* __restrict__ ql,
    const u16* __restrict__ p1h, const u16* __restrict__ p1l,
    const u16* __restrict__ vT, float* __restrict__ attn,
    u16* __restrict__ values)
{
    int bh = blockIdx.x, i0 = blockIdx.y * 32;
    int b = bh >> 4, h = bh & 15;
    int tid = threadIdx.x, w = tid >> 6, lane = tid & 63;
    int quad = lane >> 4, l16 = lane & 15;
    int wg = w >> 2, wj = w & 3;

    __shared__ __align__(16) char sm[56320];
    u16* qhs  = (u16*)sm;                 // 32*72 u16 = 4608 B
    u16* qls  = (u16*)(sm + 4608);
    u16* p1hs = (u16*)(sm + 9216);        // [2][64*72] = 18432 B
    u16* p1ls = (u16*)(sm + 27648);       // [2][64*72] = 18432 B -> 46080
    float* redm = (float*)(sm + 55296);   // [4][32] = 512 B
    float* reds = (float*)(sm + 55808);   // 512 B -> 56320
    // PV-phase aliases (q + p1 staging dead after QK/softmax barriers):
    u16* Ps  = (u16*)sm;                  // [2][2][32*72] = 18432 B
    u16* vs_ = (u16*)(sm + 18432);        // [2][2][64*72] = 36864 B -> 55296

    {   // stage q (32x64 hi/lo)
        int row = tid >> 4, c0 = (tid & 15) * 4;
        size_t g = ((size_t)bh * S_ + i0 + row) * 64 + c0;
        *(us4*)&qhs[row * 72 + c0] = *(const us4*)&qh[g];
        *(us4*)&qls[row * 72 + c0] = *(const us4*)&ql[g];
    }

    // p1 staging: thread covers (row jl, 8 cols) — tile stride 4096 elems
    const int jl = tid >> 3, c0s = (tid & 7) * 8;
    const size_t gp = ((size_t)bh * S_ + jl) * 64 + c0s;

    uint4 rha = *(const uint4*)&p1h[gp];
    uint4 rla = *(const uint4*)&p1l[gp];
    *(uint4*)&p1hs[jl * 72 + c0s] = rha;
    *(uint4*)&p1ls[jl * 72 + c0s] = rla;
    uint4 rh1 = *(const uint4*)&p1h[gp + 4096];
    uint4 rl1 = *(const uint4*)&p1l[gp + 4096];
    __syncthreads();    // q + buf0 visible

    short8 ah[2], al[2];
#pragma unroll
    for (int ch = 0; ch < 2; ++ch) {
        ah[ch] = *(short8*)&qhs[(wg * 16 + l16) * 72 + ch * 32 + quad * 8];
        al[ch] = *(short8*)&qls[(wg * 16 + l16) * 72 + ch * 32 + quad * 8];
    }

    f32x4 L[16];
    for (int t = 0; t < 16; ++t) {
        int cur = t & 1;
        uint4 rh2, rl2;
        if (t < 14) {
            size_t gn = gp + (size_t)(t + 2) * 4096;
            rh2 = *(const uint4*)&p1h[gn];
            rl2 = *(const uint4*)&p1l[gn];
        }
        int jr = wj * 16 + l16;
        const u16* Hb = &p1hs[cur * 4608 + jr * 72];
        const u16* Lb = &p1ls[cur * 4608 + jr * 72];
        short8 bh0 = *(const short8*)(Hb + quad * 8);
        short8 bh1 = *(const short8*)(Hb + 32 + quad * 8);
        short8 bl0 = *(const short8*)(Lb + quad * 8);
        short8 bl1 = *(const short8*)(Lb + 32 + quad * 8);
        f32x4 a = {};
        a = __builtin_amdgcn_mfma_f32_16x16x32_bf16(ah[0], bh0, a, 0, 0, 0);
        a = __builtin_amdgcn_mfma_f32_16x16x32_bf16(ah[1], bh1, a, 0, 0, 0);
        a = __builtin_amdgcn_mfma_f32_16x16x32_bf16(ah[0], bl0, a, 0, 0, 0);
        a = __builtin_amdgcn_mfma_f32_16x16x32_bf16(ah[1], bl1, a, 0, 0, 0);
        a = __builtin_amdgcn_mfma_f32_16x16x32_bf16(al[0], bh0, a, 0, 0, 0);
        a = __builtin_amdgcn_mfma_f32_16x16x32_bf16(al[1], bh1, a, 0, 0, 0);
        L[t] = a;
        if (t < 15) {
            *(uint4*)&p1hs[(1 - cur) * 4608 + jl * 72 + c0s] = rh1;
            *(uint4*)&p1ls[(1 - cur) * 4608 + jl * 72 + c0s] = rl1;
            if (t < 14) { rh1 = rh2; rl1 = rl2; }
            __syncthreads();
        }
    }

    // softmax
    float mrow[4], srow[4];
#pragma unroll
    for (int r = 0; r < 4; ++r) {
        float m = L[0][r];
#pragma unroll
        for (int t = 1; t < 16; ++t) m = fmaxf(m, L[t][r]);
#pragma unroll
        for (int off = 1; off < 16; off <<= 1) m = fmaxf(m, __shfl_xor(m, off, 64));
        mrow[r] = m;
    }
    if (l16 == 0)
#pragma unroll
        for (int r = 0; r < 4; ++r) redm[wj * 32 + wg * 16 + quad * 4 + r] = mrow[r];
    __syncthreads();
#pragma unroll
    for (int r = 0; r < 4; ++r) {
        int rowg = wg * 16 + quad * 4 + r;
        float m = fmaxf(fmaxf(redm[0 * 32 + rowg], redm[1 * 32 + rowg]),
                        fmaxf(redm[2 * 32 + rowg], redm[3 * 32 + rowg]));
        float s = 0.f;
#pragma unroll
        for (int t = 0; t < 16; ++t) { L[t][r] = __expf(L[t][r] - m); s += L[t][r]; }
#pragma unroll
        for (int off = 1; off < 16; off <<= 1) s += __shfl_xor(s, off, 64);
        srow[r] = s;
    }
    if (l16 == 0)
#pragma unroll
        for (int r = 0; r < 4; ++r) reds[wj * 32 + wg * 16 + quad * 4 + r] = srow[r];
    __syncthreads();
#pragma unroll
    for (int r = 0; r < 4; ++r) {
        int rowg = wg * 16 + quad * 4 + r;
        float inv = 1.0f / (reds[0 * 32 + rowg] + reds[1 * 32 + rowg] +
                            reds[2 * 32 + rowg] + reds[3 * 32 + rowg]);
        float* arow = attn + ((size_t)bh * S_ + i0 + rowg) * S_;
#pragma unroll
        for (int t = 0; t < 16; ++t) {
            float p = L[t][r] * inv;
            L[t][r] = p;
            __builtin_nontemporal_store(p, &arow[t * 64 + wj * 16 + l16]);
        }
    }

    // ---- PV (2 KV-tiles per barrier, double-buffered) ----
    const int dv = tid >> 3, jc = (tid & 7) * 8;
    const size_t gv = (size_t)(bh * 64 + dv) * S_;
    uint4 rv0 = *(const uint4*)&vT[gv + jc];
    uint4 rv1 = *(const uint4*)&vT[gv + 64 + jc];

    f32x4 acc_pv = {};
    const int d = wj * 16 + l16;
    for (int tt = 0; tt < 8; ++tt) {
        int cur = tt & 1;
        u16* Pb = Ps + cur * 4608;          // [2t][32*72]
        u16* Vb = vs_ + cur * 9216;         // [2t][64*72]
#pragma unroll
        for (int r = 0; r < 4; ++r) {
            int pr = (wg * 16 + quad * 4 + r) * 72 + wj * 16 + l16;
            Pb[pr]        = f2b(L[2 * tt][r]);
            Pb[2304 + pr] = f2b(L[2 * tt + 1][r]);
        }
        *(uint4*)&Vb[dv * 72 + jc]        = rv0;
        *(uint4*)&Vb[4608 + dv * 72 + jc] = rv1;
        __syncthreads();
        if (tt < 7) {
            rv0 = *(const uint4*)&vT[gv + (size_t)(2 * tt + 2) * 64 + jc];
            rv1 = *(const uint4*)&vT[gv + (size_t)(2 * tt + 3) * 64 + jc];
        }
#pragma unroll
        for (int tp = 0; tp < 2; ++tp)
#pragma unroll
            for (int cc = 0; cc < 64; cc += 32) {
                short8 af = *(short8*)&Pb[tp * 2304 + (wg * 16 + l16) * 72 + cc + quad * 8];
                short8 bf = *(short8*)&Vb[tp * 4608 + d * 72 + cc + quad * 8];
                acc_pv = __builtin_amdgcn_mfma_f32_16x16x32_bf16(af, bf, acc_pv, 0, 0, 0);
            }
    }
#pragma unroll
    for (int r = 0; r < 4; ++r) {
        int i = i0 + wg * 16 + quad * 4 + r;
        values[((size_t)(b * S_ + i)) * E_ + h * 64 + d] = f2b(acc_pv[r]);
    }
}

extern "C" void kernel_launch(void* const* d_in, const int* in_sizes, int n_in,
                              void* d_out, int out_size, void* d_ws, size_t ws_size,
                              hipStream_t stream)
{
    const float* x  = (const float*)d_in[0];
    const float* W0 = (const float*)d_in[1];
    const float* b0 = (const float*)d_in[2];
    const float* W1 = (const float*)d_in[3];
    const float* b1 = (const float*)d_in[4];
    const float* W2 = (const float*)d_in[5];
    const float* b2 = (const float*)d_in[6];
    const float* Wv = (const float*)d_in[7];
    const float* bv = (const float*)d_in[8];
    const float* Wo = (const float*)d_in[9];
    const float* bo = (const float*)d_in[10];
    const float* A  = (const float*)d_in[11];

    float* out  = (float*)d_out;
    float* attn = out + (size_t)B_ * S_ * E_;

    // workspace (~78.6 MB)
    u16* xh  = (u16*)d_ws;                  // 8 MB
    u16* xl  = xh + 4194304;                // 8 MB
    u16* w0h = xl + 4194304;                // 2 MB
    u16* w0l = w0h + 1048576;
    u16* w1h = w0l + 1048576;
    u16* w1l = w1h + 1048576;
    u16* p1h = w1l + 1048576;               // 8 MB
    u16* p1l = p1h + 4194304;               // 8 MB
    u16* qh  = p1l + 4194304;               // 8 MB
    u16* ql  = qh + 4194304;                // 8 MB
    u16* vT  = ql + 4194304;                // 8 MB (heads-transposed v)
    u16* values = vT + 4194304;             // 8 MB (bf16 natural)
    u16* MTh = values + 4194304;            // 512 KB (transposed M hi)
    u16* MTl = MTh + 262144;                // 512 KB
    u16* wob = MTl + 262144;                // 2 MB (bf16 Wo)
    // xsum partials [16][4][1024] fp32 = 256 KB — aliased onto p1h (written
    // by gemm_mid strictly after t2k_M consumed xsum_p).
    float* xsum_p = (float*)p1h;
    // wvb aliased onto values region: consumed by gemm_mid, which completes
    // before logits_softmax_pv writes values.
    u16* wvb = values;

    prep<<<8448, 256, 0, stream>>>(x, W0, W1, Wv, Wo, xsum_p,
                                   xh, xl, w0h, w0l, w1h, w1l, wvb, wob);
    t2k_M<<<dim3(16, 4), 256, 0, stream>>>(W2, b2, xsum_p, A, MTh, MTl);

    gemm_mid<<<1024, 256, 0, stream>>>(xh, xl, w0h, w0l, w1h, w1l,
                                       b0, b1, MTh, MTl, qh, ql, p1h, p1l,
                                       wvb, bv, vT);

    logits_softmax_pv<<<dim3(64, 32), 512, 0, stream>>>(qh, ql, p1h, p1l, vT, attn, values);

    gemm_fin<<<dim3(32, 16), 256, 0, stream>>>(values, wob, bo, out);
}